// Round 1
// baseline (17605.634 us; speedup 1.0000x reference)
//
#include <hip/hip_runtime.h>
#include <hip/hip_bf16.h>

// Sizes (fixed by the problem)
#define BATCH 128
#define SEQ   512
#define IND   512
#define FSD   128
#define HS    512
#define G4    (4 * HS)   // 2048
#define G2    (2 * HS)   // 1024

// bf16 helpers on raw ushort (avoid __hip_bfloat16 ABI differences)
static __device__ __forceinline__ unsigned short f2bf(float f) {
    unsigned int u = __float_as_uint(f);
    unsigned int r = (u + 0x7fffu + ((u >> 16) & 1u)) >> 16;
    return (unsigned short)r;
}
static __device__ __forceinline__ float bf2f(unsigned short b) {
    return __uint_as_float(((unsigned int)b) << 16);
}
static __device__ __forceinline__ float sigmoidf_(float x) {
    return 1.0f / (1.0f + __expf(-x));
}

// ---------------------------------------------------------------------------
// Kernel 1: convert+permute U_f [512][2048] f32 -> Ub [k][j][gate] bf16
// Ub[(k*512 + j)*4 + g] = U_f[k][g*512 + j]
// ---------------------------------------------------------------------------
__global__ __launch_bounds__(256)
void uconv_kernel(const float* __restrict__ Uf, unsigned short* __restrict__ Ub) {
    int idx = blockIdx.x * 256 + threadIdx.x;     // 0 .. 512*2048-1
    int k = idx >> 11;
    int r = idx & 2047;
    int j = r >> 2, g = r & 3;
    Ub[idx] = f2bf(Uf[(size_t)k * G4 + g * HS + j]);
}

// ---------------------------------------------------------------------------
// Kernel 2: lz = sigmoid(field@Wz[:, :512]+bz) * tanh(field@Wz[:, 512:]+bz)
// Output layout: lz[s][b][j] bf16
// Grid: (BATCH, SEQ/8), block 256. Each block: one b, 8 consecutive s.
// ---------------------------------------------------------------------------
__global__ __launch_bounds__(256)
void lz_kernel(const float* __restrict__ field, const float* __restrict__ Wz,
               const float* __restrict__ biasz, unsigned short* __restrict__ lzOut) {
    __shared__ float fs[8][FSD];
    int b = blockIdx.x, s0 = blockIdx.y * 8;
    int tid = threadIdx.x;
    for (int u = tid; u < 8 * FSD; u += 256) {
        int r = u >> 7, k = u & 127;
        fs[r][k] = field[((size_t)b * SEQ + s0 + r) * FSD + k];
    }
    __syncthreads();
    #pragma unroll
    for (int jj = 0; jj < 2; ++jj) {
        int j = tid + jj * 256;
        float accl[8] = {0,0,0,0,0,0,0,0}, accz[8] = {0,0,0,0,0,0,0,0};
        for (int k = 0; k < FSD; ++k) {
            float wl = Wz[(size_t)k * G2 + j];
            float wz = Wz[(size_t)k * G2 + HS + j];
            #pragma unroll
            for (int r = 0; r < 8; ++r) {
                accl[r] += fs[r][k] * wl;
                accz[r] += fs[r][k] * wz;
            }
        }
        float bl = biasz[j], bz = biasz[HS + j];
        #pragma unroll
        for (int r = 0; r < 8; ++r) {
            float l = sigmoidf_(accl[r] + bl);
            float z = tanhf(accz[r] + bz);
            lzOut[(((size_t)(s0 + r)) * BATCH + b) * HS + j] = f2bf(l * z);
        }
    }
}

// ---------------------------------------------------------------------------
// Kernel 3: x_proj GEMM: C[row=(s*128+b)][col] = word[b][s][:] @ W_f + bias_f
// M=65536 (row = s*BATCH+b), N=2048, K=512.  Output bf16 [S][B][4H].
// Tiled f32: BM=64, BN=128, TK=32, 256 threads, 4x8 accum per thread.
// ---------------------------------------------------------------------------
#define BM 64
#define BN 128
#define TK 32
__global__ __launch_bounds__(256)
void xproj_kernel(const float* __restrict__ word, const float* __restrict__ Wf,
                  const float* __restrict__ bias, unsigned short* __restrict__ xp) {
    __shared__ float As[TK][BM];
    __shared__ float Bs[TK][BN];
    int tid = threadIdx.x;
    int row0 = blockIdx.x * BM;
    int col0 = blockIdx.y * BN;
    int tx = tid & 15;          // 0..15 (col group: 8 cols each)
    int ty = tid >> 4;          // 0..15 (row group: rows ty + {0,16,32,48})
    float acc[4][8];
    #pragma unroll
    for (int i = 0; i < 4; ++i)
        #pragma unroll
        for (int c = 0; c < 8; ++c) acc[i][c] = 0.f;

    // A-load assignment: thread loads 8 consecutive k at (arow, ak0)
    int arow = tid & 63;
    int ak0 = (tid >> 6) * 8;
    int grow = row0 + arow;
    int b_ = grow & 127, s_ = grow >> 7;
    const float* aptr = word + ((size_t)b_ * SEQ + s_) * IND;
    // B-load assignment: thread loads 16 consecutive cols at (bk, bc0)
    int bk = tid >> 3;
    int bc0 = (tid & 7) * 16;

    for (int k0 = 0; k0 < IND; k0 += TK) {
        #pragma unroll
        for (int u = 0; u < 8; u += 4) {
            float4 v = *(const float4*)(aptr + k0 + ak0 + u);
            As[ak0 + u + 0][arow] = v.x;
            As[ak0 + u + 1][arow] = v.y;
            As[ak0 + u + 2][arow] = v.z;
            As[ak0 + u + 3][arow] = v.w;
        }
        #pragma unroll
        for (int u = 0; u < 16; u += 4) {
            float4 v = *(const float4*)(Wf + (size_t)(k0 + bk) * G4 + col0 + bc0 + u);
            *(float4*)&Bs[bk][bc0 + u] = v;
        }
        __syncthreads();
        #pragma unroll
        for (int kk = 0; kk < TK; ++kk) {
            float a0 = As[kk][ty], a1 = As[kk][ty + 16];
            float a2 = As[kk][ty + 32], a3 = As[kk][ty + 48];
            float bb[8];
            #pragma unroll
            for (int c = 0; c < 8; ++c) bb[c] = Bs[kk][tx * 8 + c];
            #pragma unroll
            for (int c = 0; c < 8; ++c) {
                acc[0][c] += a0 * bb[c];
                acc[1][c] += a1 * bb[c];
                acc[2][c] += a2 * bb[c];
                acc[3][c] += a3 * bb[c];
            }
        }
        __syncthreads();
    }
    #pragma unroll
    for (int rm = 0; rm < 4; ++rm) {
        int gr = row0 + ty + rm * 16;
        #pragma unroll
        for (int c = 0; c < 8; ++c) {
            int gc = col0 + tx * 8 + c;
            xp[(size_t)gr * G4 + gc] = f2bf(acc[rm][c] + bias[gc]);
        }
    }
}

// ---------------------------------------------------------------------------
// Kernel 4: the recurrence. One block per batch element, 512 threads = one
// hidden index each. h lives in LDS; c in a register. 512 sequential steps.
// Ub is bf16 [k][j][gate] so each (k, thread) is one 8B coalesced load.
// ---------------------------------------------------------------------------
__global__ __launch_bounds__(512)
void rec_kernel(const unsigned short* __restrict__ xp,
                const unsigned short* __restrict__ lz,
                const unsigned short* __restrict__ Ub,
                float* __restrict__ out) {
    __shared__ float hs[HS];
    int b = blockIdx.x;
    int j = threadIdx.x;
    float c = 0.f;
    hs[j] = 0.f;
    __syncthreads();
    const size_t HSEQ = (size_t)BATCH * SEQ * HS;

    for (int t = 0; t < SEQ; ++t) {
        size_t xb = ((size_t)t * BATCH + b) * G4;
        float gi = bf2f(xp[xb + j]);
        float gf = bf2f(xp[xb + HS + j]);
        float gg = bf2f(xp[xb + 2 * HS + j]);
        float go = bf2f(xp[xb + 3 * HS + j]);

        #pragma unroll 8
        for (int k = 0; k < HS; ++k) {
            float hk = hs[k];
            ushort4 u = *(const ushort4*)(Ub + ((size_t)k * HS + j) * 4);
            gi += hk * bf2f(u.x);
            gf += hk * bf2f(u.y);
            gg += hk * bf2f(u.z);
            go += hk * bf2f(u.w);
        }

        float i_ = sigmoidf_(gi);
        float f_ = sigmoidf_(gf + 1.0f);
        float g_ = tanhf(gg);
        float o_ = sigmoidf_(go);
        c = f_ * c + i_ * g_ + bf2f(lz[((size_t)t * BATCH + b) * HS + j]);
        float h = o_ * tanhf(c);
        out[((size_t)b * SEQ + t) * HS + j] = h;
        __syncthreads();
        hs[j] = h;
        __syncthreads();
    }
    // h_T, c_T
    out[HSEQ + (size_t)b * HS + j] = hs[j];
    out[HSEQ + (size_t)BATCH * HS + (size_t)b * HS + j] = c;
}

// ---------------------------------------------------------------------------
extern "C" void kernel_launch(void* const* d_in, const int* in_sizes, int n_in,
                              void* d_out, int out_size, void* d_ws, size_t ws_size,
                              hipStream_t stream) {
    const float* word   = (const float*)d_in[0];
    const float* field  = (const float*)d_in[1];
    const float* Wf     = (const float*)d_in[2];
    const float* Wz     = (const float*)d_in[3];
    const float* Uf     = (const float*)d_in[4];
    const float* bias_f = (const float*)d_in[5];
    const float* biasz  = (const float*)d_in[6];
    float* out = (float*)d_out;

    // Workspace layout (bytes):
    //   xp : bf16 [S][B][4H]  = 512*128*2048*2 = 268,435,456
    //   lz : bf16 [S][B][H]   = 512*128*512*2  =  67,108,864
    //   Ub : bf16 [K][H][4]   = 512*512*4*2    =   2,097,152
    unsigned short* xp  = (unsigned short*)d_ws;
    unsigned short* lzb = (unsigned short*)((char*)d_ws + (size_t)SEQ * BATCH * G4 * 2);
    unsigned short* Ub  = (unsigned short*)((char*)lzb + (size_t)SEQ * BATCH * HS * 2);

    uconv_kernel<<<(IND * G4) / 256, 256, 0, stream>>>(Uf, Ub);

    dim3 gl(BATCH, SEQ / 8);
    lz_kernel<<<gl, 256, 0, stream>>>(field, Wz, biasz, lzb);

    dim3 gx((SEQ * BATCH) / BM, G4 / BN);
    xproj_kernel<<<gx, 256, 0, stream>>>(word, Wf, bias_f, xp);

    rec_kernel<<<BATCH, HS, 0, stream>>>(xp, lzb, Ub, out);
}